// Round 2
// baseline (2645.892 us; speedup 1.0000x reference)
//
#include <hip/hip_runtime.h>
#include <cfloat>

#define B_SZ    4096
#define D_MOD   768
#define DICT    24576
#define K_TOP   64
#define CAND_CAP 256
#define MARGIN  0.02f   // >> worst-case fp32 GEMM accumulation error (~3.5e-3)

// ---------------------------------------------------------------------------
// float <-> order-preserving uint key
// ---------------------------------------------------------------------------
__device__ __forceinline__ unsigned f2k(float f) {
  unsigned u = __float_as_uint(f);
  return (u & 0x80000000u) ? ~u : (u | 0x80000000u);
}
__device__ __forceinline__ float k2f(unsigned k) {
  unsigned u = (k & 0x80000000u) ? (k & 0x7FFFFFFFu) : ~k;
  return __uint_as_float(u);
}

// ---------------------------------------------------------------------------
// Kernel 1: encoder GEMM  C[B_SZ,DICT] = x[B_SZ,D_MOD] @ W_enc[DICT,D_MOD]^T + b
// fp32 VALU. Accuracy only needs to beat MARGIN (selection is re-ranked in fp64).
// 128x128 tile, BK=16, 256 threads, 8x8 micro-tile/thread.
// ---------------------------------------------------------------------------
#define BM 128
#define BN 128
#define BK 16
#define LDP (BM + 4)

__global__ __launch_bounds__(256) void enc_gemm(
    const float* __restrict__ A,    // [B_SZ, D_MOD]
    const float* __restrict__ W,    // [DICT, D_MOD]
    const float* __restrict__ bias, // [DICT]
    float* __restrict__ C)          // [B_SZ, DICT]
{
  __shared__ float As[BK][LDP];
  __shared__ float Bs[BK][LDP];

  const int tid = threadIdx.x;
  const int n0 = blockIdx.x * BN;
  const int m0 = blockIdx.y * BM;
  const int tx = tid & 15;
  const int ty = tid >> 4;
  const int lrow = tid >> 2;
  const int lc4  = tid & 3;

  const float* Aptr  = A + (size_t)(m0 + lrow) * D_MOD + lc4 * 4;
  const float* Aptr2 = Aptr + (size_t)64 * D_MOD;
  const float* Wptr  = W + (size_t)(n0 + lrow) * D_MOD + lc4 * 4;
  const float* Wptr2 = Wptr + (size_t)64 * D_MOD;

  float acc[8][8];
  #pragma unroll
  for (int i = 0; i < 8; ++i)
    #pragma unroll
    for (int j = 0; j < 8; ++j) acc[i][j] = 0.f;

  for (int kt = 0; kt < D_MOD; kt += BK) {
    float4 a0 = *(const float4*)(Aptr  + kt);
    float4 a1 = *(const float4*)(Aptr2 + kt);
    float4 b0 = *(const float4*)(Wptr  + kt);
    float4 b1 = *(const float4*)(Wptr2 + kt);
    __syncthreads();
    As[lc4*4+0][lrow] = a0.x;  As[lc4*4+1][lrow] = a0.y;
    As[lc4*4+2][lrow] = a0.z;  As[lc4*4+3][lrow] = a0.w;
    As[lc4*4+0][64+lrow] = a1.x;  As[lc4*4+1][64+lrow] = a1.y;
    As[lc4*4+2][64+lrow] = a1.z;  As[lc4*4+3][64+lrow] = a1.w;
    Bs[lc4*4+0][lrow] = b0.x;  Bs[lc4*4+1][lrow] = b0.y;
    Bs[lc4*4+2][lrow] = b0.z;  Bs[lc4*4+3][lrow] = b0.w;
    Bs[lc4*4+0][64+lrow] = b1.x;  Bs[lc4*4+1][64+lrow] = b1.y;
    Bs[lc4*4+2][64+lrow] = b1.z;  Bs[lc4*4+3][64+lrow] = b1.w;
    __syncthreads();
    #pragma unroll
    for (int k = 0; k < BK; ++k) {
      float a[8], b[8];
      *(float4*)&a[0] = *(const float4*)&As[k][ty*4];
      *(float4*)&a[4] = *(const float4*)&As[k][64 + ty*4];
      *(float4*)&b[0] = *(const float4*)&Bs[k][tx*4];
      *(float4*)&b[4] = *(const float4*)&Bs[k][64 + tx*4];
      #pragma unroll
      for (int i = 0; i < 8; ++i)
        #pragma unroll
        for (int j = 0; j < 8; ++j) acc[i][j] += a[i] * b[j];
    }
  }

  float4 bs0 = *(const float4*)(bias + n0 + tx*4);
  float4 bs1 = *(const float4*)(bias + n0 + 64 + tx*4);
  #pragma unroll
  for (int i = 0; i < 8; ++i) {
    int r = m0 + ((i < 4) ? (ty*4 + i) : (64 + ty*4 + i - 4));
    float* cp = C + (size_t)r * DICT + n0 + tx*4;
    float4 o0 = {acc[i][0]+bs0.x, acc[i][1]+bs0.y, acc[i][2]+bs0.z, acc[i][3]+bs0.w};
    float4 o1 = {acc[i][4]+bs1.x, acc[i][5]+bs1.y, acc[i][6]+bs1.z, acc[i][7]+bs1.w};
    *(float4*)cp = o0;
    *(float4*)(cp + 64) = o1;
  }
}

// ---------------------------------------------------------------------------
// Kernel 2: per-row approximate top-k boundary + margin-candidate emission.
// Zeroes the whole row; emits candidate indices with val >= kth_fp32 - MARGIN.
// ---------------------------------------------------------------------------
#define TK_CAP 6144

__device__ __forceinline__ int block_reduce_sum_256(int v, volatile int* wsum, int tid) {
  #pragma unroll
  for (int off = 32; off > 0; off >>= 1) v += __shfl_down(v, off, 64);
  __syncthreads();
  if ((tid & 63) == 0) wsum[tid >> 6] = v;
  __syncthreads();
  return wsum[0] + wsum[1] + wsum[2] + wsum[3];
}

__global__ __launch_bounds__(256) void topk_kernel(
    float* __restrict__ acts,       // [B_SZ, DICT] in: pre_acts, out: zeros
    int*   __restrict__ cand_idx,   // [B_SZ, CAND_CAP]
    int*   __restrict__ cand_cnt)   // [B_SZ]
{
  const int row = blockIdx.x;
  const int tid = threadIdx.x;
  float* rp = acts + (size_t)row * DICT;

  __shared__ unsigned ckey[TK_CAP];
  __shared__ int      cidx[TK_CAP];
  __shared__ int      wsum[4];
  __shared__ int      s_cnt, s_out;

  float4 v[24];
  #pragma unroll
  for (int c = 0; c < 24; ++c) v[c] = *((const float4*)rp + tid + 256*c);

  // threshold ladder (pre_acts ~ N(0, sigma~1): count(>2.2) ~ 220..500)
  int c0=0, c1=0, c2=0;
  #pragma unroll
  for (int c = 0; c < 24; ++c) {
    float e[4] = {v[c].x, v[c].y, v[c].z, v[c].w};
    #pragma unroll
    for (int j = 0; j < 4; ++j) {
      c0 += (e[j] > 2.2f) ? 1 : 0;
      c1 += (e[j] > 1.5f) ? 1 : 0;
      c2 += (e[j] > 0.5f) ? 1 : 0;
    }
  }
  int t0 = block_reduce_sum_256(c0, wsum, tid);
  int t1 = block_reduce_sum_256(c1, wsum, tid);
  int t2 = block_reduce_sum_256(c2, wsum, tid);
  float thr;
  if      (t0 >= K_TOP + 40 && t0 <= TK_CAP) thr = 2.2f;   // +40: margin cands too
  else if (t1 >= K_TOP + 40 && t1 <= TK_CAP) thr = 1.5f;
  else if (t2 >= K_TOP + 40 && t2 <= TK_CAP) thr = 0.5f;
  else                                       thr = -4.0f;  // unreachable for this data

  if (tid == 0) { s_cnt = 0; s_out = 0; }
  __syncthreads();

  // collect candidates > thr into LDS
  #pragma unroll
  for (int c = 0; c < 24; ++c) {
    float e[4] = {v[c].x, v[c].y, v[c].z, v[c].w};
    int base = (tid + 256*c) * 4;
    #pragma unroll
    for (int j = 0; j < 4; ++j) {
      if (e[j] > thr) {
        int s = atomicAdd(&s_cnt, 1);
        if (s < TK_CAP) { ckey[s] = f2k(e[j]); cidx[s] = base + j; }
      }
    }
  }
  __syncthreads();
  const int m = (s_cnt < TK_CAP) ? s_cnt : TK_CAP;

  // radix bisection: exact fp32 64th-largest key among candidates
  unsigned prefix = 0;
  int r = K_TOP;
  for (int b = 31; b >= 0; --b) {
    unsigned bit = 1u << b;
    int c = 0;
    for (int i = tid; i < m; i += 256) {
      unsigned k = ckey[i];
      bool ok = (b == 31) ? true : ((k >> (b+1)) == (prefix >> (b+1)));
      if (ok && (k & bit)) ++c;
    }
    c = block_reduce_sum_256(c, wsum, tid);
    if (c >= r) prefix |= bit; else r -= c;
  }

  // zero the whole row (winners scattered back by rerank_kernel)
  float4 z = {0.f, 0.f, 0.f, 0.f};
  #pragma unroll
  for (int c = 0; c < 24; ++c) *((float4*)rp + tid + 256*c) = z;

  // emit margin candidates: val >= kth_fp32 - MARGIN
  const unsigned mkey = f2k(k2f(prefix) - MARGIN);
  __syncthreads();
  for (int i = tid; i < m; i += 256) {
    if (ckey[i] >= mkey) {
      int s = atomicAdd(&s_out, 1);
      if (s < CAND_CAP) cand_idx[(size_t)row * CAND_CAP + s] = cidx[i];
    }
  }
  __syncthreads();
  if (tid == 0) cand_cnt[row] = (s_out < CAND_CAP) ? s_out : CAND_CAP;
}

// ---------------------------------------------------------------------------
// Kernel 3: fp64 exact re-rank of candidates; scatter winners.
// One block (4 waves) per row; one wave per candidate dot.
// fp64 sums are order-independent at this scale (err ~1e-13 << gaps ~5e-3).
// ---------------------------------------------------------------------------
__global__ __launch_bounds__(256) void rerank_kernel(
    const float* __restrict__ x,      // [B_SZ, D_MOD]
    const float* __restrict__ W,      // [DICT, D_MOD]
    const float* __restrict__ bias,   // [DICT]
    const int*   __restrict__ cand_idx,
    const int*   __restrict__ cand_cnt,
    float* __restrict__ acts,         // [B_SZ, DICT] (zeroed rows)
    float* __restrict__ tk_val,       // [B_SZ, K_TOP]
    int*   __restrict__ tk_idx)       // [B_SZ, K_TOP]
{
  const int row  = blockIdx.x;
  const int tid  = threadIdx.x;
  const int lane = tid & 63;
  const int wv   = tid >> 6;

  __shared__ double xs[D_MOD];
  __shared__ double cval[CAND_CAP];
  __shared__ int    cidx_s[CAND_CAP];

  const int cnt = cand_cnt[row];

  for (int i = tid; i < D_MOD; i += 256)
    xs[i] = (double)x[(size_t)row * D_MOD + i];
  if (tid < CAND_CAP)
    cidx_s[tid] = (tid < cnt) ? cand_idx[(size_t)row * CAND_CAP + tid] : 0x7fffffff;
  __syncthreads();

  // one wave per candidate: exact fp64 dot of x_row with W[f,:]
  for (int c = wv; c < cnt; c += 4) {
    const int f = cidx_s[c];
    const float* w = W + (size_t)f * D_MOD;
    double s = 0.0;
    #pragma unroll
    for (int j = 0; j < D_MOD / 64; ++j)
      s = fma((double)w[lane + 64*j], xs[lane + 64*j], s);
    #pragma unroll
    for (int off = 32; off > 0; off >>= 1) s += __shfl_down(s, off, 64);
    if (lane == 0) cval[c] = s + (double)bias[f];
  }
  __syncthreads();

  // all-pairs rank (<=256 cands); ties -> lower index first (lax.top_k order)
  const bool active = (tid < cnt);
  const double myv = active ? cval[tid] : -DBL_MAX;
  const int    myi = active ? cidx_s[tid] : 0x7fffffff;
  int rank = 0;
  for (int j = 0; j < cnt; ++j) {
    double vj = cval[j];
    rank += (vj > myv || (vj == myv && cidx_s[j] < myi)) ? 1 : 0;
  }
  if (active && rank < K_TOP) {
    float a = fmaxf((float)myv, 0.f);
    tk_val[(size_t)row * K_TOP + rank] = a;
    tk_idx[(size_t)row * K_TOP + rank] = myi;
    acts[(size_t)row * DICT + myi] = a;
  }
}

// ---------------------------------------------------------------------------
// Kernel 4: W_dec [D_MOD, DICT] -> W_decT [DICT, D_MOD]
// ---------------------------------------------------------------------------
__global__ __launch_bounds__(256) void transpose_wdec(
    const float* __restrict__ Wd, float* __restrict__ WdT)
{
  __shared__ float tile[32][33];
  const int x = blockIdx.x * 32 + threadIdx.x;
  const int y0 = blockIdx.y * 32;
  #pragma unroll
  for (int i = 0; i < 32; i += 8)
    tile[threadIdx.y + i][threadIdx.x] = Wd[(size_t)(y0 + threadIdx.y + i) * DICT + x];
  __syncthreads();
  const int xo = y0 + threadIdx.x;
  const int yo = blockIdx.x * 32;
  #pragma unroll
  for (int i = 0; i < 32; i += 8)
    WdT[(size_t)(yo + threadIdx.y + i) * D_MOD + xo] = tile[threadIdx.x][threadIdx.y + i];
}

// ---------------------------------------------------------------------------
// Kernel 5: sparse decoder  recon[b,:] = sum_j val_j * W_dec[:, idx_j]
// ---------------------------------------------------------------------------
__global__ __launch_bounds__(256) void decoder_kernel(
    const float* __restrict__ tk_val, const int* __restrict__ tk_idx,
    const float* __restrict__ WdT,    // [DICT, D_MOD] (if useT)
    const float* __restrict__ Wd,     // [D_MOD, DICT] (fallback)
    float* __restrict__ recon, int useT)
{
  const int row = blockIdx.x;
  const int tid = threadIdx.x;
  __shared__ float sval[K_TOP];
  __shared__ int   sidx[K_TOP];
  if (tid < K_TOP) { sval[tid] = tk_val[row*K_TOP + tid]; sidx[tid] = tk_idx[row*K_TOP + tid]; }
  __syncthreads();
  float a0 = 0.f, a1 = 0.f, a2 = 0.f;
  if (useT) {
    #pragma unroll 8
    for (int j = 0; j < K_TOP; ++j) {
      float s = sval[j];
      const float* w = WdT + (size_t)sidx[j] * D_MOD;
      a0 += s * w[tid]; a1 += s * w[tid + 256]; a2 += s * w[tid + 512];
    }
  } else {
    #pragma unroll 8
    for (int j = 0; j < K_TOP; ++j) {
      float s = sval[j]; int f = sidx[j];
      a0 += s * Wd[(size_t)(tid      ) * DICT + f];
      a1 += s * Wd[(size_t)(tid + 256) * DICT + f];
      a2 += s * Wd[(size_t)(tid + 512) * DICT + f];
    }
  }
  float* rp = recon + (size_t)row * D_MOD;
  rp[tid] = a0; rp[tid + 256] = a1; rp[tid + 512] = a2;
}

// ---------------------------------------------------------------------------
extern "C" void kernel_launch(void* const* d_in, const int* in_sizes, int n_in,
                              void* d_out, int out_size, void* d_ws, size_t ws_size,
                              hipStream_t stream) {
  const float* x     = (const float*)d_in[0];
  const float* W_enc = (const float*)d_in[1];
  const float* b_enc = (const float*)d_in[2];
  const float* W_dec = (const float*)d_in[3];
  // d_in[4] = k (scalar, always 64) -- compiled in as K_TOP

  float* recon = (float*)d_out;
  float* acts  = recon + (size_t)B_SZ * D_MOD;

  float* tk_val   = (float*)d_ws;
  int*   tk_idx   = (int*)(tk_val + (size_t)B_SZ * K_TOP);
  int*   cand_cnt = (int*)(tk_idx + (size_t)B_SZ * K_TOP);
  int*   cand_idx = cand_cnt + B_SZ;
  float* WdT      = (float*)(cand_idx + (size_t)B_SZ * CAND_CAP);
  size_t base = (size_t)B_SZ * K_TOP * 8 + (size_t)B_SZ * 4 + (size_t)B_SZ * CAND_CAP * 4;
  size_t need_T = base + (size_t)DICT * D_MOD * 4;
  int useT = (ws_size >= need_T) ? 1 : 0;

  if (useT)
    hipLaunchKernelGGL(transpose_wdec, dim3(DICT/32, D_MOD/32), dim3(32, 8), 0, stream,
                       W_dec, WdT);
  hipLaunchKernelGGL(enc_gemm, dim3(DICT/BN, B_SZ/BM), dim3(256), 0, stream,
                     x, W_enc, b_enc, acts);
  hipLaunchKernelGGL(topk_kernel, dim3(B_SZ), dim3(256), 0, stream,
                     acts, cand_idx, cand_cnt);
  hipLaunchKernelGGL(rerank_kernel, dim3(B_SZ), dim3(256), 0, stream,
                     x, W_enc, b_enc, cand_idx, cand_cnt, acts, tk_val, tk_idx);
  hipLaunchKernelGGL(decoder_kernel, dim3(B_SZ), dim3(256), 0, stream,
                     tk_val, tk_idx, WdT, W_dec, recon, useT);
}

// Round 3
// 1555.347 us; speedup vs baseline: 1.7012x; 1.7012x over previous
//
#include <hip/hip_runtime.h>
#include <cfloat>

#define B_SZ    4096
#define D_MOD   768
#define DICT    24576
#define K_TOP   64
#define CAND_CAP 256
#define MARGIN  0.02f   // >> split-bf16 GEMM error (~1e-4 worst case)
#define K3      2304    // 3 * D_MOD  (hi*hi + hi*lo + lo*hi via K-concat)

typedef __attribute__((ext_vector_type(8))) short short8;
typedef __attribute__((ext_vector_type(4))) float floatx4;

// ---------------------------------------------------------------------------
// helpers
// ---------------------------------------------------------------------------
__device__ __forceinline__ unsigned f2k(float f) {
  unsigned u = __float_as_uint(f);
  return (u & 0x80000000u) ? ~u : (u | 0x80000000u);
}
__device__ __forceinline__ float k2f(unsigned k) {
  unsigned u = (k & 0x80000000u) ? (k & 0x7FFFFFFFu) : ~k;
  return __uint_as_float(u);
}
__device__ __forceinline__ unsigned short f2bf(float f) {  // RNE
  unsigned u = __float_as_uint(f);
  unsigned r = (u + 0x7fffu + ((u >> 16) & 1u)) >> 16;
  return (unsigned short)r;
}
__device__ __forceinline__ float bf2f(unsigned short b) {
  return __uint_as_float(((unsigned)b) << 16);
}
__device__ __forceinline__ void gload_lds16(const void* g, void* l) {
  __builtin_amdgcn_global_load_lds(
      (const __attribute__((address_space(1))) unsigned*)g,
      (__attribute__((address_space(3))) unsigned*)l, 16, 0, 0);
}

// ---------------------------------------------------------------------------
// Kernel 0: split fp32 -> K-concat bf16 triple
// pat 0 (x): [hi, hi, lo]    pat 1 (W_enc): [hi, lo, hi]
// ---------------------------------------------------------------------------
__global__ __launch_bounds__(256) void cvt_split(
    const float* __restrict__ S, short* __restrict__ D, int n, int pat)
{
  int idx = blockIdx.x * 256 + threadIdx.x;
  if (idx >= n) return;
  int r = idx / D_MOD, c = idx - r * D_MOD;
  float f = S[idx];
  unsigned short hi = f2bf(f);
  unsigned short lo = f2bf(f - bf2f(hi));
  short* d = D + (size_t)r * K3 + c;
  d[0] = (short)hi;
  d[D_MOD]     = pat ? (short)lo : (short)hi;
  d[2 * D_MOD] = pat ? (short)hi : (short)lo;
}

// ---------------------------------------------------------------------------
// Kernel 1a: MFMA encoder GEMM over K-concat bf16.
// C[B_SZ,DICT] = A3[B_SZ,K3] . W3[DICT,K3]^T + bias  (fp32 accum)
// 128x128 tile, 256 thr = 4 waves (2x2 of 64x64), 16x16x32 MFMA, BK=32.
// ---------------------------------------------------------------------------
__global__ __launch_bounds__(256) void enc_gemm_mfma(
    const short* __restrict__ A3,   // [B_SZ, K3]
    const short* __restrict__ W3,   // [DICT, K3]
    const float* __restrict__ bias,
    float* __restrict__ C)
{
  __shared__ short As[128][32];
  __shared__ short Bs[128][32];

  const int tid = threadIdx.x;
  const int l   = tid & 63;
  const int w   = tid >> 6;
  const int n0  = blockIdx.x * 128;
  const int m0  = blockIdx.y * 128;
  const int wr  = w >> 1, wc = w & 1;

  // staging: wave w, inst i stages rows [(w*2+i)*16, +16); lane l -> row +(l>>2), 16B at (l&3)*8
  const int srow = (w * 2) * 16 + (l >> 2);
  const int kc   = (l & 3) * 8;
  const short* gA0 = A3 + (size_t)(m0 + srow) * K3 + kc;
  const short* gA1 = gA0 + (size_t)16 * K3;
  const short* gB0 = W3 + (size_t)(n0 + srow) * K3 + kc;
  const short* gB1 = gB0 + (size_t)16 * K3;
  short* lA0 = &As[(w * 2) * 16][0];
  short* lA1 = lA0 + 16 * 32;
  short* lB0 = &Bs[(w * 2) * 16][0];
  short* lB1 = lB0 + 16 * 32;

  floatx4 acc[4][4];
  #pragma unroll
  for (int i = 0; i < 4; ++i)
    #pragma unroll
    for (int j = 0; j < 4; ++j) acc[i][j] = (floatx4){0.f, 0.f, 0.f, 0.f};

  const int fr = l & 15;        // fragment row (m/n within 16-tile)
  const int fq = (l >> 4) * 8;  // fragment k offset

  for (int kt = 0; kt < K3; kt += 32) {
    __syncthreads();                       // prev iter's ds_reads done
    gload_lds16(gA0 + kt, lA0);
    gload_lds16(gA1 + kt, lA1);
    gload_lds16(gB0 + kt, lB0);
    gload_lds16(gB1 + kt, lB1);
    __syncthreads();                       // staging landed (vmcnt drain)
    short8 af[4], bf[4];
    #pragma unroll
    for (int t = 0; t < 4; ++t) {
      af[t] = *(const short8*)&As[wr * 64 + t * 16 + fr][fq];
      bf[t] = *(const short8*)&Bs[wc * 64 + t * 16 + fr][fq];
    }
    #pragma unroll
    for (int i = 0; i < 4; ++i)
      #pragma unroll
      for (int j = 0; j < 4; ++j)
        acc[i][j] = __builtin_amdgcn_mfma_f32_16x16x32_bf16(af[i], bf[j], acc[i][j], 0, 0, 0);
  }

  // epilogue: C/D layout col=lane&15 (n), row=(lane>>4)*4+reg (m)
  const int rq = (l >> 4) * 4;
  #pragma unroll
  for (int j = 0; j < 4; ++j) {
    const int n = n0 + wc * 64 + j * 16 + fr;
    const float bv = bias[n];
    #pragma unroll
    for (int i = 0; i < 4; ++i) {
      const int mb = m0 + wr * 64 + i * 16 + rq;
      #pragma unroll
      for (int r = 0; r < 4; ++r)
        C[(size_t)(mb + r) * DICT + n] = acc[i][j][r] + bv;
    }
  }
}

// ---------------------------------------------------------------------------
// Kernel 1b (fallback, ws too small): fp32 VALU GEMM
// ---------------------------------------------------------------------------
#define BM 128
#define BN 128
#define BK 16
#define LDP (BM + 4)

__global__ __launch_bounds__(256) void enc_gemm(
    const float* __restrict__ A, const float* __restrict__ W,
    const float* __restrict__ bias, float* __restrict__ C)
{
  __shared__ float Asf[BK][LDP];
  __shared__ float Bsf[BK][LDP];

  const int tid = threadIdx.x;
  const int n0 = blockIdx.x * BN;
  const int m0 = blockIdx.y * BM;
  const int tx = tid & 15;
  const int ty = tid >> 4;
  const int lrow = tid >> 2;
  const int lc4  = tid & 3;

  const float* Aptr  = A + (size_t)(m0 + lrow) * D_MOD + lc4 * 4;
  const float* Aptr2 = Aptr + (size_t)64 * D_MOD;
  const float* Wptr  = W + (size_t)(n0 + lrow) * D_MOD + lc4 * 4;
  const float* Wptr2 = Wptr + (size_t)64 * D_MOD;

  float acc[8][8];
  #pragma unroll
  for (int i = 0; i < 8; ++i)
    #pragma unroll
    for (int j = 0; j < 8; ++j) acc[i][j] = 0.f;

  for (int kt = 0; kt < D_MOD; kt += BK) {
    float4 a0 = *(const float4*)(Aptr  + kt);
    float4 a1 = *(const float4*)(Aptr2 + kt);
    float4 b0 = *(const float4*)(Wptr  + kt);
    float4 b1 = *(const float4*)(Wptr2 + kt);
    __syncthreads();
    Asf[lc4*4+0][lrow] = a0.x;  Asf[lc4*4+1][lrow] = a0.y;
    Asf[lc4*4+2][lrow] = a0.z;  Asf[lc4*4+3][lrow] = a0.w;
    Asf[lc4*4+0][64+lrow] = a1.x;  Asf[lc4*4+1][64+lrow] = a1.y;
    Asf[lc4*4+2][64+lrow] = a1.z;  Asf[lc4*4+3][64+lrow] = a1.w;
    Bsf[lc4*4+0][lrow] = b0.x;  Bsf[lc4*4+1][lrow] = b0.y;
    Bsf[lc4*4+2][lrow] = b0.z;  Bsf[lc4*4+3][lrow] = b0.w;
    Bsf[lc4*4+0][64+lrow] = b1.x;  Bsf[lc4*4+1][64+lrow] = b1.y;
    Bsf[lc4*4+2][64+lrow] = b1.z;  Bsf[lc4*4+3][64+lrow] = b1.w;
    __syncthreads();
    #pragma unroll
    for (int k = 0; k < BK; ++k) {
      float a[8], b[8];
      *(float4*)&a[0] = *(const float4*)&Asf[k][ty*4];
      *(float4*)&a[4] = *(const float4*)&Asf[k][64 + ty*4];
      *(float4*)&b[0] = *(const float4*)&Bsf[k][tx*4];
      *(float4*)&b[4] = *(const float4*)&Bsf[k][64 + tx*4];
      #pragma unroll
      for (int i = 0; i < 8; ++i)
        #pragma unroll
        for (int j = 0; j < 8; ++j) acc[i][j] += a[i] * b[j];
    }
  }

  float4 bs0 = *(const float4*)(bias + n0 + tx*4);
  float4 bs1 = *(const float4*)(bias + n0 + 64 + tx*4);
  #pragma unroll
  for (int i = 0; i < 8; ++i) {
    int r = m0 + ((i < 4) ? (ty*4 + i) : (64 + ty*4 + i - 4));
    float* cp = C + (size_t)r * DICT + n0 + tx*4;
    float4 o0 = {acc[i][0]+bs0.x, acc[i][1]+bs0.y, acc[i][2]+bs0.z, acc[i][3]+bs0.w};
    float4 o1 = {acc[i][4]+bs1.x, acc[i][5]+bs1.y, acc[i][6]+bs1.z, acc[i][7]+bs1.w};
    *(float4*)cp = o0;
    *(float4*)(cp + 64) = o1;
  }
}

// ---------------------------------------------------------------------------
// Kernel 2: per-row fp32 top-k boundary + margin-candidate emission; zero row.
// ---------------------------------------------------------------------------
#define TK_CAP 6144

__device__ __forceinline__ int block_reduce_sum_256(int v, volatile int* wsum, int tid) {
  #pragma unroll
  for (int off = 32; off > 0; off >>= 1) v += __shfl_down(v, off, 64);
  __syncthreads();
  if ((tid & 63) == 0) wsum[tid >> 6] = v;
  __syncthreads();
  return wsum[0] + wsum[1] + wsum[2] + wsum[3];
}

__global__ __launch_bounds__(256) void topk_kernel(
    float* __restrict__ acts, int* __restrict__ cand_idx, int* __restrict__ cand_cnt)
{
  const int row = blockIdx.x;
  const int tid = threadIdx.x;
  float* rp = acts + (size_t)row * DICT;

  __shared__ unsigned ckey[TK_CAP];
  __shared__ int      cidx[TK_CAP];
  __shared__ int      wsum[4];
  __shared__ int      s_cnt, s_out;

  float4 v[24];
  #pragma unroll
  for (int c = 0; c < 24; ++c) v[c] = *((const float4*)rp + tid + 256*c);

  int c0=0, c1=0, c2=0;
  #pragma unroll
  for (int c = 0; c < 24; ++c) {
    float e[4] = {v[c].x, v[c].y, v[c].z, v[c].w};
    #pragma unroll
    for (int j = 0; j < 4; ++j) {
      c0 += (e[j] > 2.2f) ? 1 : 0;
      c1 += (e[j] > 1.5f) ? 1 : 0;
      c2 += (e[j] > 0.5f) ? 1 : 0;
    }
  }
  int t0 = block_reduce_sum_256(c0, wsum, tid);
  int t1 = block_reduce_sum_256(c1, wsum, tid);
  int t2 = block_reduce_sum_256(c2, wsum, tid);
  float thr;
  if      (t0 >= K_TOP + 40 && t0 <= TK_CAP) thr = 2.2f;
  else if (t1 >= K_TOP + 40 && t1 <= TK_CAP) thr = 1.5f;
  else if (t2 >= K_TOP + 40 && t2 <= TK_CAP) thr = 0.5f;
  else                                       thr = -4.0f;

  if (tid == 0) { s_cnt = 0; s_out = 0; }
  __syncthreads();

  #pragma unroll
  for (int c = 0; c < 24; ++c) {
    float e[4] = {v[c].x, v[c].y, v[c].z, v[c].w};
    int base = (tid + 256*c) * 4;
    #pragma unroll
    for (int j = 0; j < 4; ++j) {
      if (e[j] > thr) {
        int s = atomicAdd(&s_cnt, 1);
        if (s < TK_CAP) { ckey[s] = f2k(e[j]); cidx[s] = base + j; }
      }
    }
  }
  __syncthreads();
  const int m = (s_cnt < TK_CAP) ? s_cnt : TK_CAP;

  unsigned prefix = 0;
  int r = K_TOP;
  for (int b = 31; b >= 0; --b) {
    unsigned bit = 1u << b;
    int c = 0;
    for (int i = tid; i < m; i += 256) {
      unsigned k = ckey[i];
      bool ok = (b == 31) ? true : ((k >> (b+1)) == (prefix >> (b+1)));
      if (ok && (k & bit)) ++c;
    }
    c = block_reduce_sum_256(c, wsum, tid);
    if (c >= r) prefix |= bit; else r -= c;
  }

  float4 z = {0.f, 0.f, 0.f, 0.f};
  #pragma unroll
  for (int c = 0; c < 24; ++c) *((float4*)rp + tid + 256*c) = z;

  const unsigned mkey = f2k(k2f(prefix) - MARGIN);
  __syncthreads();
  for (int i = tid; i < m; i += 256) {
    if (ckey[i] >= mkey) {
      int s = atomicAdd(&s_out, 1);
      if (s < CAND_CAP) cand_idx[(size_t)row * CAND_CAP + s] = cidx[i];
    }
  }
  __syncthreads();
  if (tid == 0) cand_cnt[row] = (s_out < CAND_CAP) ? s_out : CAND_CAP;
}

// ---------------------------------------------------------------------------
// Kernel 3: fp64 exact re-rank of candidates; scatter winners.
// ---------------------------------------------------------------------------
__global__ __launch_bounds__(256) void rerank_kernel(
    const float* __restrict__ x, const float* __restrict__ W,
    const float* __restrict__ bias,
    const int* __restrict__ cand_idx, const int* __restrict__ cand_cnt,
    float* __restrict__ acts, float* __restrict__ tk_val, int* __restrict__ tk_idx)
{
  const int row  = blockIdx.x;
  const int tid  = threadIdx.x;
  const int lane = tid & 63;
  const int wv   = tid >> 6;

  __shared__ double xs[D_MOD];
  __shared__ double cval[CAND_CAP];
  __shared__ int    cidx_s[CAND_CAP];

  const int cnt = cand_cnt[row];

  for (int i = tid; i < D_MOD; i += 256)
    xs[i] = (double)x[(size_t)row * D_MOD + i];
  if (tid < CAND_CAP)
    cidx_s[tid] = (tid < cnt) ? cand_idx[(size_t)row * CAND_CAP + tid] : 0x7fffffff;
  __syncthreads();

  for (int c = wv; c < cnt; c += 4) {
    const int f = cidx_s[c];
    const float* wrow = W + (size_t)f * D_MOD;
    double s = 0.0;
    #pragma unroll
    for (int j = 0; j < D_MOD / 64; ++j)
      s = fma((double)wrow[lane + 64*j], xs[lane + 64*j], s);
    #pragma unroll
    for (int off = 32; off > 0; off >>= 1) s += __shfl_down(s, off, 64);
    if (lane == 0) cval[c] = s + (double)bias[f];
  }
  __syncthreads();

  const bool active = (tid < cnt);
  const double myv = active ? cval[tid] : -DBL_MAX;
  const int    myi = active ? cidx_s[tid] : 0x7fffffff;
  int rank = 0;
  for (int j = 0; j < cnt; ++j) {
    double vj = cval[j];
    rank += (vj > myv || (vj == myv && cidx_s[j] < myi)) ? 1 : 0;
  }
  if (active && rank < K_TOP) {
    float a = fmaxf((float)myv, 0.f);
    tk_val[(size_t)row * K_TOP + rank] = a;
    tk_idx[(size_t)row * K_TOP + rank] = myi;
    acts[(size_t)row * DICT + myi] = a;
  }
}

// ---------------------------------------------------------------------------
// Kernel 4: W_dec [D_MOD, DICT] -> W_decT [DICT, D_MOD]
// ---------------------------------------------------------------------------
__global__ __launch_bounds__(256) void transpose_wdec(
    const float* __restrict__ Wd, float* __restrict__ WdT)
{
  __shared__ float tile[32][33];
  const int x = blockIdx.x * 32 + threadIdx.x;
  const int y0 = blockIdx.y * 32;
  #pragma unroll
  for (int i = 0; i < 32; i += 8)
    tile[threadIdx.y + i][threadIdx.x] = Wd[(size_t)(y0 + threadIdx.y + i) * DICT + x];
  __syncthreads();
  const int xo = y0 + threadIdx.x;
  const int yo = blockIdx.x * 32;
  #pragma unroll
  for (int i = 0; i < 32; i += 8)
    WdT[(size_t)(yo + threadIdx.y + i) * D_MOD + xo] = tile[threadIdx.x][threadIdx.y + i];
}

// ---------------------------------------------------------------------------
// Kernel 5: sparse decoder
// ---------------------------------------------------------------------------
__global__ __launch_bounds__(256) void decoder_kernel(
    const float* __restrict__ tk_val, const int* __restrict__ tk_idx,
    const float* __restrict__ WdT, const float* __restrict__ Wd,
    float* __restrict__ recon, int useT)
{
  const int row = blockIdx.x;
  const int tid = threadIdx.x;
  __shared__ float sval[K_TOP];
  __shared__ int   sidx[K_TOP];
  if (tid < K_TOP) { sval[tid] = tk_val[row*K_TOP + tid]; sidx[tid] = tk_idx[row*K_TOP + tid]; }
  __syncthreads();
  float a0 = 0.f, a1 = 0.f, a2 = 0.f;
  if (useT) {
    #pragma unroll 8
    for (int j = 0; j < K_TOP; ++j) {
      float s = sval[j];
      const float* w = WdT + (size_t)sidx[j] * D_MOD;
      a0 += s * w[tid]; a1 += s * w[tid + 256]; a2 += s * w[tid + 512];
    }
  } else {
    #pragma unroll 8
    for (int j = 0; j < K_TOP; ++j) {
      float s = sval[j]; int f = sidx[j];
      a0 += s * Wd[(size_t)(tid      ) * DICT + f];
      a1 += s * Wd[(size_t)(tid + 256) * DICT + f];
      a2 += s * Wd[(size_t)(tid + 512) * DICT + f];
    }
  }
  float* rp = recon + (size_t)row * D_MOD;
  rp[tid] = a0; rp[tid + 256] = a1; rp[tid + 512] = a2;
}

// ---------------------------------------------------------------------------
extern "C" void kernel_launch(void* const* d_in, const int* in_sizes, int n_in,
                              void* d_out, int out_size, void* d_ws, size_t ws_size,
                              hipStream_t stream) {
  const float* x     = (const float*)d_in[0];
  const float* W_enc = (const float*)d_in[1];
  const float* b_enc = (const float*)d_in[2];
  const float* W_dec = (const float*)d_in[3];

  float* recon = (float*)d_out;
  float* acts  = recon + (size_t)B_SZ * D_MOD;

  float* tk_val   = (float*)d_ws;
  int*   tk_idx   = (int*)(tk_val + (size_t)B_SZ * K_TOP);
  int*   cand_cnt = (int*)(tk_idx + (size_t)B_SZ * K_TOP);
  int*   cand_idx = cand_cnt + B_SZ;
  float* WdT      = (float*)(cand_idx + (size_t)B_SZ * CAND_CAP);
  short* A3       = (short*)(WdT + (size_t)DICT * D_MOD);
  short* W3       = A3 + (size_t)B_SZ * K3;

  size_t base     = (size_t)B_SZ * K_TOP * 8 + (size_t)B_SZ * 4 + (size_t)B_SZ * CAND_CAP * 4;
  size_t need_T   = base + (size_t)DICT * D_MOD * 4;
  size_t need_mf  = need_T + ((size_t)B_SZ + DICT) * K3 * 2;
  int useT  = (ws_size >= need_T) ? 1 : 0;
  int useMF = (ws_size >= need_mf) ? 1 : 0;

  if (useT)
    hipLaunchKernelGGL(transpose_wdec, dim3(DICT/32, D_MOD/32), dim3(32, 8), 0, stream,
                       W_dec, WdT);
  if (useMF) {
    hipLaunchKernelGGL(cvt_split, dim3((B_SZ*D_MOD + 255)/256), dim3(256), 0, stream,
                       x, A3, B_SZ*D_MOD, 0);
    hipLaunchKernelGGL(cvt_split, dim3((DICT*D_MOD + 255)/256), dim3(256), 0, stream,
                       W_enc, W3, DICT*D_MOD, 1);
    hipLaunchKernelGGL(enc_gemm_mfma, dim3(DICT/128, B_SZ/128), dim3(256), 0, stream,
                       A3, W3, b_enc, acts);
  } else {
    hipLaunchKernelGGL(enc_gemm, dim3(DICT/BN, B_SZ/BM), dim3(256), 0, stream,
                       x, W_enc, b_enc, acts);
  }
  hipLaunchKernelGGL(topk_kernel, dim3(B_SZ), dim3(256), 0, stream,
                     acts, cand_idx, cand_cnt);
  hipLaunchKernelGGL(rerank_kernel, dim3(B_SZ), dim3(256), 0, stream,
                     x, W_enc, b_enc, cand_idx, cand_cnt, acts, tk_val, tk_idx);
  hipLaunchKernelGGL(decoder_kernel, dim3(B_SZ), dim3(256), 0, stream,
                     tk_val, tk_idx, WdT, W_dec, recon, useT);
}